// Round 7
// baseline (193.887 us; speedup 1.0000x reference)
//
#include <hip/hip_runtime.h>

#define BB 4
#define CCH 384
#define HH 56
#define WWD 56
#define HW 3136
#define S2 49
#define S2P 52
#define D2 192
#define K2 25
#define XSP2 36         // xs leading dim for 32-px tiles (+4 pad)

// ---- Kernel 1: GT[i][j] = sum_d Wk[d][i] * Wq[d][j]  (384x384, K=192) ----
__global__ __launch_bounds__(256) void gt_k(const float* __restrict__ Wk,
                                            const float* __restrict__ Wq,
                                            float* __restrict__ GT) {
    __shared__ __align__(16) float As[D2 * 32];
    __shared__ __align__(16) float Bs[D2 * 32];
    int bi = blockIdx.x % 12, bj = blockIdx.x / 12;
    int t = threadIdx.x;
#pragma unroll
    for (int k = 0; k < 6; k++) {
        int idx = t + 256 * k;
        int d = idx >> 3, q = idx & 7;
        *(float4*)&As[d * 32 + 4 * q] = *(const float4*)&Wk[(size_t)d * CCH + bi * 32 + 4 * q];
        *(float4*)&Bs[d * 32 + 4 * q] = *(const float4*)&Wq[(size_t)d * CCH + bj * 32 + 4 * q];
    }
    __syncthreads();
    int ti = t >> 4, tj = t & 15;
    float a00 = 0.f, a01 = 0.f, a10 = 0.f, a11 = 0.f;
#pragma unroll 8
    for (int d = 0; d < D2; d++) {
        float2 av = *(float2*)&As[d * 32 + 2 * ti];
        float2 bv = *(float2*)&Bs[d * 32 + 2 * tj];
        a00 += av.x * bv.x; a01 += av.x * bv.y;
        a10 += av.y * bv.x; a11 += av.y * bv.y;
    }
    int gi = bi * 32 + 2 * ti, gj = bj * 32 + 2 * tj;
    *(float2*)&GT[(size_t)gi * CCH + gj]       = make_float2(a00, a01);
    *(float2*)&GT[(size_t)(gi + 1) * CCH + gj] = make_float2(a10, a11);
}

// ---- Kernel 2a: coalesced adaptive pool: block per (b,c), f4 sweep + LDS bins
__global__ __launch_bounds__(256) void pool2_k(const float* __restrict__ ctx,
                                               float* __restrict__ ctx_p) {
    __shared__ float bin[S2];
    int bc = blockIdx.x;
    int t  = threadIdx.x;
    if (t < S2) bin[t] = 0.f;
    __syncthreads();
    const float* img = ctx + (size_t)bc * HW;
#pragma unroll
    for (int k = 0; k < 4; k++) {
        int i = t + 256 * k;
        if (k < 3 || t < 16) {
            float4 a = *(const float4*)&img[4 * i];
            float s4 = a.x + a.y + a.z + a.w;
            int h  = i / 14;
            int rc = i - 14 * h;
            int sy = h >> 3, sx = rc >> 1;
            atomicAdd(&bin[sy * 7 + sx], s4);
        }
    }
    __syncthreads();
    if (t < S2) ctx_p[(size_t)bc * S2 + t] = bin[t] * (1.f / 64.f);
}

// ---- Kernel 2b: M[b,c,s] = sum_i ctx_p[b,i,s] * GT[i][c]  (per (b,s) block)
__global__ __launch_bounds__(384) void m2_k(const float* __restrict__ ctx_p,
                                            const float* __restrict__ GT,
                                            float* __restrict__ M) {
    __shared__ float v[CCH];
    int b = blockIdx.x / S2, s = blockIdx.x % S2;
    int t = threadIdx.x;
    v[t] = ctx_p[((size_t)(b * CCH) + t) * S2 + s];
    __syncthreads();
    float acc = 0.f;
#pragma unroll 8
    for (int i = 0; i < CCH; i++)
        acc += v[i] * GT[(size_t)i * CCH + t];
    M[((size_t)(b * CCH + t)) * S2P + s] = acc;
    if (s < 3) M[((size_t)(b * CCH + t)) * S2P + 49 + s] = 0.f;
}

// ---- Kernel 3: scores = x^T M, softmax(49), dyn = Wwd*A ----
// 32 px/block, 256 thr, register-prefetch pipelined staging, grid B*98.
// Roles: pxg=t&7 (px quad), sg=(t>>3)&3 (s quad-group), slice=t>>5 (8x12 rows).
__global__ __launch_bounds__(256) void attn_k(const float* __restrict__ x,
                                              const float* __restrict__ M,
                                              const float* __restrict__ Wwd,
                                              float* __restrict__ dyn) {
    __shared__ __align__(16) float smem[96 * XSP2 + 96 * S2P]; // xs | Ms ; red aliases
    __shared__ __align__(16) float sc[32 * S2P];
    __shared__ __align__(16) float wl[K2 * S2P];
    float* xs  = smem;                // [96][36]
    float* Ms  = smem + 96 * XSP2;    // [96][52]
    float* red = smem;                // [4][32][52] = 6656 floats (aliases)

    int b  = blockIdx.x / 98;
    int n0 = (blockIdx.x % 98) * 32;
    int t  = threadIdx.x;
    int pxg = t & 7, sg = (t >> 3) & 3, slice = t >> 5;

    float4 acc4[4][4];
#pragma unroll
    for (int k = 0; k < 4; k++)
#pragma unroll
        for (int j = 0; j < 4; j++) acc4[k][j] = make_float4(0.f, 0.f, 0.f, 0.f);

    const float* xb = x + (size_t)b * CCH * HW + n0;
    const float* Mb = M + (size_t)b * CCH * S2P;

    // staging registers
    float4 xg[3], mg[5];
    int xr = t >> 3, xq = t & 3 /*unused pattern differs*/;
    (void)xq;

    // prologue: load chunk 0
    {
        const float* src = Mb;
#pragma unroll
        for (int k = 0; k < 3; k++) {
            int idx = t + 256 * k;
            int r = idx >> 3, q = idx & 7;
            xg[k] = *(const float4*)&xb[(size_t)r * HW + 4 * q];
        }
#pragma unroll
        for (int k = 0; k < 4; k++) mg[k] = *(const float4*)&src[4 * (t + 256 * k)];
        if (t < 224) mg[4] = *(const float4*)&src[4 * (t + 1024)];
    }

    for (int ch = 0; ch < 4; ch++) {
        // commit staged registers to LDS
#pragma unroll
        for (int k = 0; k < 3; k++) {
            int idx = t + 256 * k;
            int r = idx >> 3, q = idx & 7;
            *(float4*)&xs[r * XSP2 + 4 * q] = xg[k];
        }
#pragma unroll
        for (int k = 0; k < 4; k++) *(float4*)&Ms[4 * (t + 256 * k)] = mg[k];
        if (t < 224) *(float4*)&Ms[4 * (t + 1024)] = mg[4];
        __syncthreads();

        // issue prefetch for chunk ch+1 (consumed after next barrier)
        if (ch < 3) {
            int c0n = (ch + 1) * 96;
            const float* srcn = Mb + (size_t)c0n * S2P;
#pragma unroll
            for (int k = 0; k < 3; k++) {
                int idx = t + 256 * k;
                int r = idx >> 3, q = idx & 7;
                xg[k] = *(const float4*)&xb[(size_t)(c0n + r) * HW + 4 * q];
            }
#pragma unroll
            for (int k = 0; k < 4; k++) mg[k] = *(const float4*)&srcn[4 * (t + 256 * k)];
            if (t < 224) mg[4] = *(const float4*)&srcn[4 * (t + 1024)];
        }

        // compute on current chunk
        int rbase = 12 * slice;
#pragma unroll
        for (int m = 0; m < 12; m++) {
            int r = rbase + m;
            const float4 xv = *(const float4*)&xs[r * XSP2 + 4 * pxg];
#pragma unroll
            for (int k = 0; k < 3; k++) {
                int g = sg + 4 * k;
                const float4 mv = *(const float4*)&Ms[r * S2P + 4 * g];
                acc4[k][0].x += mv.x * xv.x; acc4[k][0].y += mv.x * xv.y;
                acc4[k][0].z += mv.x * xv.z; acc4[k][0].w += mv.x * xv.w;
                acc4[k][1].x += mv.y * xv.x; acc4[k][1].y += mv.y * xv.y;
                acc4[k][1].z += mv.y * xv.z; acc4[k][1].w += mv.y * xv.w;
                acc4[k][2].x += mv.z * xv.x; acc4[k][2].y += mv.z * xv.y;
                acc4[k][2].z += mv.z * xv.z; acc4[k][2].w += mv.z * xv.w;
                acc4[k][3].x += mv.w * xv.x; acc4[k][3].y += mv.w * xv.y;
                acc4[k][3].z += mv.w * xv.z; acc4[k][3].w += mv.w * xv.w;
            }
            if (sg == 0) {
                const float4 mv = *(const float4*)&Ms[r * S2P + 48];
                acc4[3][0].x += mv.x * xv.x; acc4[3][0].y += mv.x * xv.y;
                acc4[3][0].z += mv.x * xv.z; acc4[3][0].w += mv.x * xv.w;
                acc4[3][1].x += mv.y * xv.x; acc4[3][1].y += mv.y * xv.y;
                acc4[3][1].z += mv.y * xv.z; acc4[3][1].w += mv.y * xv.w;
                acc4[3][2].x += mv.z * xv.x; acc4[3][2].y += mv.z * xv.y;
                acc4[3][2].z += mv.z * xv.z; acc4[3][2].w += mv.z * xv.w;
                acc4[3][3].x += mv.w * xv.x; acc4[3][3].y += mv.w * xv.y;
                acc4[3][3].z += mv.w * xv.z; acc4[3][3].w += mv.w * xv.w;
            }
        }
        __syncthreads();
    }

    // pair-combine slices 2w,2w+1 (lanes l and l^32)
#pragma unroll
    for (int k = 0; k < 4; k++)
#pragma unroll
        for (int j = 0; j < 4; j++) {
            acc4[k][j].x += __shfl_xor(acc4[k][j].x, 32);
            acc4[k][j].y += __shfl_xor(acc4[k][j].y, 32);
            acc4[k][j].z += __shfl_xor(acc4[k][j].z, 32);
            acc4[k][j].w += __shfl_xor(acc4[k][j].w, 32);
        }

    // lanes <32 of each wave write pair-partials -> red[wave][32px][52]
    if ((t & 63) < 32) {
        int wv = t >> 6;
        float* rb = red + (size_t)wv * 32 * S2P;
#pragma unroll
        for (int k = 0; k < 4; k++) {
            int g = sg + 4 * k;
            if (g < 13) {
                *(float4*)&rb[(4 * pxg + 0) * S2P + 4 * g] =
                    make_float4(acc4[k][0].x, acc4[k][1].x, acc4[k][2].x, acc4[k][3].x);
                *(float4*)&rb[(4 * pxg + 1) * S2P + 4 * g] =
                    make_float4(acc4[k][0].y, acc4[k][1].y, acc4[k][2].y, acc4[k][3].y);
                *(float4*)&rb[(4 * pxg + 2) * S2P + 4 * g] =
                    make_float4(acc4[k][0].z, acc4[k][1].z, acc4[k][2].z, acc4[k][3].z);
                *(float4*)&rb[(4 * pxg + 3) * S2P + 4 * g] =
                    make_float4(acc4[k][0].w, acc4[k][1].w, acc4[k][2].w, acc4[k][3].w);
            }
        }
    }
    __syncthreads();

    // final reduce over 4 waves -> sc   (32*13 = 416 = 256 + 160)
#pragma unroll
    for (int pass = 0; pass < 2; pass++) {
        int o = t + 256 * pass;
        if (pass == 0 || t < 160) {
            int px = o / 13, q = o - px * 13;
            float4 ssum = make_float4(0.f, 0.f, 0.f, 0.f);
#pragma unroll
            for (int wv = 0; wv < 4; wv++) {
                float4 vv = *(float4*)&red[(size_t)(wv * 32 + px) * S2P + 4 * q];
                ssum.x += vv.x; ssum.y += vv.y; ssum.z += vv.z; ssum.w += vv.w;
            }
            *(float4*)&sc[px * S2P + 4 * q] = ssum;
        }
    }
    __syncthreads();

    // softmax: 8 lanes per pixel (all 256 threads)
    {
        int px = t >> 3, li = t & 7;
        float mx = -3.4e38f;
#pragma unroll
        for (int k = 0; k < 7; k++) { int s = li + 8 * k; if (s < S2) mx = fmaxf(mx, sc[px * S2P + s]); }
        mx = fmaxf(mx, __shfl_xor(mx, 1, 8));
        mx = fmaxf(mx, __shfl_xor(mx, 2, 8));
        mx = fmaxf(mx, __shfl_xor(mx, 4, 8));
        float e[7]; float sum = 0.f;
#pragma unroll
        for (int k = 0; k < 7; k++) {
            int s = li + 8 * k;
            if (s < S2) { e[k] = __expf(sc[px * S2P + s] - mx); sum += e[k]; }
        }
        sum += __shfl_xor(sum, 1, 8);
        sum += __shfl_xor(sum, 2, 8);
        sum += __shfl_xor(sum, 4, 8);
        float inv = 1.f / sum;
#pragma unroll
        for (int k = 0; k < 7; k++) {
            int s = li + 8 * k;
            if (s < S2) sc[px * S2P + s] = e[k] * inv;
        }
    }
    // stage Wwd (padded cols 49..51 = 0): 1300 = 5*256 + 20
#pragma unroll
    for (int k = 0; k < 5; k++) {
        int i = t + 256 * k;
        int j = i / S2P, ss = i - j * S2P;
        wl[i] = (ss < S2) ? Wwd[j * S2 + ss] : 0.f;
    }
    if (t < 20) {
        int i = t + 1280;
        int j = i / S2P, ss = i - j * S2P;
        wl[i] = (ss < S2) ? Wwd[j * S2 + ss] : 0.f;
    }
    __syncthreads();

    // dyn[b,j,n0+px] = sum_s wl[j,s]*sc[px,s]   (800 outs: 3*256 + 32)
    float* dynb = dyn + (size_t)b * K2 * HW + n0;
#pragma unroll
    for (int pass = 0; pass < 4; pass++) {
        int o = t + 256 * pass;
        if (pass < 3 || t < 32) {
            int j = o >> 5, px = o & 31;
            float a = 0.f;
#pragma unroll
            for (int q = 0; q < 13; q++) {
                float4 wv = *(float4*)&wl[j * S2P + 4 * q];
                float4 pv = *(float4*)&sc[px * S2P + 4 * q];
                a += wv.x * pv.x + wv.y * pv.y + wv.z * pv.z + wv.w * pv.w;
            }
            dynb[(size_t)j * HW + px] = a;
        }
    }
}

// ---- Kernel 4: 5x5 dynamic stencil; 16 ch x 8-row stripe ----
__global__ __launch_bounds__(256) void out_k(const float* __restrict__ x,
                                             const float* __restrict__ dyn,
                                             float* __restrict__ out) {
    __shared__ __align__(16) float xt[16][12][60];
    int blk    = blockIdx.x;
    int stripe = blk % 7;
    int cg     = (blk / 7) % 24;
    int b      = blk / (7 * 24);
    int h0 = stripe * 8;
    int c0 = cg * 16;
    int t  = threadIdx.x;
    const float* xb = x + ((size_t)(b * CCH + c0)) * HW;

    if (t < 192) {
        int cc = t / 12, r = t % 12;
        xt[cc][r][0] = 0.f; xt[cc][r][1] = 0.f;
        xt[cc][r][58] = 0.f; xt[cc][r][59] = 0.f;
    }
#pragma unroll
    for (int k = 0; k < 11; k++) {
        int idx = t + 256 * k;
        if (k < 10 || t < 128) {
            int cc  = idx / 168;
            int rem = idx - cc * 168;
            int r   = rem / 14;
            int q   = rem - r * 14;
            int h   = h0 - 2 + r;
            float4 v = make_float4(0.f, 0.f, 0.f, 0.f);
            if ((unsigned)h < (unsigned)HH)
                v = *(const float4*)&xb[(size_t)cc * HW + h * WWD + 4 * q];
            xt[cc][r][2 + 4 * q + 0] = v.x;
            xt[cc][r][2 + 4 * q + 1] = v.y;
            xt[cc][r][2 + 4 * q + 2] = v.z;
            xt[cc][r][2 + 4 * q + 3] = v.w;
        }
    }

    bool act = t < 224;
    int r  = t / 28;
    int w0 = 2 * (t % 28);
    int n  = (h0 + r) * WWD + w0;
    float2 dv[K2];
    if (act) {
        const float* db = dyn + (size_t)b * K2 * HW + n;
#pragma unroll
        for (int j = 0; j < K2; j++) dv[j] = *(const float2*)&db[(size_t)j * HW];
    }
    __syncthreads();
    if (!act) return;

    float* ob = out + ((size_t)(b * CCH + c0)) * HW + n;
#pragma unroll
    for (int cc = 0; cc < 16; cc++) {
        float ax = 0.f, ay = 0.f;
#pragma unroll
        for (int rr = 0; rr < 5; rr++) {
            int lr = r + rr;
            float2 p0 = *(float2*)&xt[cc][lr][w0];
            float2 p1 = *(float2*)&xt[cc][lr][w0 + 2];
            float2 p2 = *(float2*)&xt[cc][lr][w0 + 4];
            int o5 = rr * 5;
            ax += p0.x * dv[o5].x     + p0.y * dv[o5 + 1].x + p1.x * dv[o5 + 2].x
                + p1.y * dv[o5 + 3].x + p2.x * dv[o5 + 4].x;
            ay += p0.y * dv[o5].y     + p1.x * dv[o5 + 1].y + p1.y * dv[o5 + 2].y
                + p2.x * dv[o5 + 3].y + p2.y * dv[o5 + 4].y;
        }
        *(float2*)&ob[(size_t)cc * HW] = make_float2(ax, ay);
    }
}

extern "C" void kernel_launch(void* const* d_in, const int* in_sizes, int n_in,
                              void* d_out, int out_size, void* d_ws, size_t ws_size,
                              hipStream_t stream) {
    const float* x   = (const float*)d_in[0];
    const float* ctx = (const float*)d_in[1];
    const float* Wq  = (const float*)d_in[2];
    const float* Wk  = (const float*)d_in[3];
    const float* Wwd = (const float*)d_in[4];
    float* out = (float*)d_out;
    float* ws  = (float*)d_ws;

    float* GT    = ws;                           // 384*384   = 147456
    float* M     = ws + 147456;                  // B*384*52  =  79872
    float* dyn   = ws + 147456 + 79872;          // B*25*3136 = 313600
    float* ctx_p = ws + 147456 + 79872 + 313600; // B*384*49  =  75264

    gt_k<<<12 * 12, 256, 0, stream>>>(Wk, Wq, GT);
    pool2_k<<<BB * CCH, 256, 0, stream>>>(ctx, ctx_p);
    m2_k<<<BB * S2, 384, 0, stream>>>(ctx_p, GT, M);
    attn_k<<<BB * 98, 256, 0, stream>>>(x, M, Wwd, dyn);
    out_k<<<BB * 24 * 7, 256, 0, stream>>>(x, dyn, out);
}

// Round 8
// 184.267 us; speedup vs baseline: 1.0522x; 1.0522x over previous
//
#include <hip/hip_runtime.h>

#define BB 4
#define CCH 384
#define HH 56
#define WWD 56
#define HW 3136
#define S2 49
#define S2P 52
#define D2 192
#define K2 25
#define XSP 20          // xs leading dim for 16-px tiles

// ---- Kernel 1: GT[i][j] = sum_d Wk[d][i] * Wq[d][j]  (384x384, K=192) ----
__global__ __launch_bounds__(256) void gt_k(const float* __restrict__ Wk,
                                            const float* __restrict__ Wq,
                                            float* __restrict__ GT) {
    __shared__ __align__(16) float As[D2 * 32];
    __shared__ __align__(16) float Bs[D2 * 32];
    int bi = blockIdx.x % 12, bj = blockIdx.x / 12;
    int t = threadIdx.x;
#pragma unroll
    for (int k = 0; k < 6; k++) {
        int idx = t + 256 * k;
        int d = idx >> 3, q = idx & 7;
        *(float4*)&As[d * 32 + 4 * q] = *(const float4*)&Wk[(size_t)d * CCH + bi * 32 + 4 * q];
        *(float4*)&Bs[d * 32 + 4 * q] = *(const float4*)&Wq[(size_t)d * CCH + bj * 32 + 4 * q];
    }
    __syncthreads();
    int ti = t >> 4, tj = t & 15;
    float a00 = 0.f, a01 = 0.f, a10 = 0.f, a11 = 0.f;
#pragma unroll 8
    for (int d = 0; d < D2; d++) {
        float2 av = *(float2*)&As[d * 32 + 2 * ti];
        float2 bv = *(float2*)&Bs[d * 32 + 2 * tj];
        a00 += av.x * bv.x; a01 += av.x * bv.y;
        a10 += av.y * bv.x; a11 += av.y * bv.y;
    }
    int gi = bi * 32 + 2 * ti, gj = bj * 32 + 2 * tj;
    *(float2*)&GT[(size_t)gi * CCH + gj]       = make_float2(a00, a01);
    *(float2*)&GT[(size_t)(gi + 1) * CCH + gj] = make_float2(a10, a11);
}

// ---- Kernel 2a: coalesced adaptive pool: block per (b,c), f4 sweep + LDS bins
__global__ __launch_bounds__(256) void pool2_k(const float* __restrict__ ctx,
                                               float* __restrict__ ctx_p) {
    __shared__ float bin[S2];
    int bc = blockIdx.x;
    int t  = threadIdx.x;
    if (t < S2) bin[t] = 0.f;
    __syncthreads();
    const float* img = ctx + (size_t)bc * HW;
#pragma unroll
    for (int k = 0; k < 4; k++) {
        int i = t + 256 * k;
        if (k < 3 || t < 16) {
            float4 a = *(const float4*)&img[4 * i];
            float s4 = a.x + a.y + a.z + a.w;
            int h  = i / 14;
            int rc = i - 14 * h;
            int sy = h >> 3, sx = rc >> 1;
            atomicAdd(&bin[sy * 7 + sx], s4);
        }
    }
    __syncthreads();
    if (t < S2) ctx_p[(size_t)bc * S2 + t] = bin[t] * (1.f / 64.f);
}

// ---- Kernel 2b: M[b,c,s] = sum_i ctx_p[b,i,s] * GT[i][c]  (per (b,s) block)
__global__ __launch_bounds__(384) void m2_k(const float* __restrict__ ctx_p,
                                            const float* __restrict__ GT,
                                            float* __restrict__ M) {
    __shared__ float v[CCH];
    int b = blockIdx.x / S2, s = blockIdx.x % S2;
    int t = threadIdx.x;
    v[t] = ctx_p[((size_t)(b * CCH) + t) * S2 + s];
    __syncthreads();
    float acc = 0.f;
#pragma unroll 8
    for (int i = 0; i < CCH; i++)
        acc += v[i] * GT[(size_t)i * CCH + t];
    M[((size_t)(b * CCH + t)) * S2P + s] = acc;
    if (s < 3) M[((size_t)(b * CCH + t)) * S2P + 49 + s] = 0.f;
}

// ---- Kernel 3a: partial scores for ONE 96-channel chunk ----
// grid = 4ch * 4b * 196 tiles; 256 thr; 16 px/block.
// Roles: pxg=t&3, sg=(t>>2)&3, slice=t>>4 (16 slices x 6 rows).
__global__ __launch_bounds__(256) void attn_a(const float* __restrict__ x,
                                              const float* __restrict__ M,
                                              float* __restrict__ part) {
    __shared__ __align__(16) float smem[96 * XSP + 96 * S2P];  // xs | Ms ; red aliases
    float* xs  = smem;               // [96][20]
    float* Ms  = smem + 96 * XSP;    // [96][52]
    float* red = smem;               // [4][16][52] = 3328 floats (aliases)

    int blk  = blockIdx.x;
    int tile = blk % 196;
    int b    = (blk / 196) & 3;
    int ch   = blk / 784;
    int n0   = tile * 16;
    int c0   = ch * 96;
    int t    = threadIdx.x;
    int pxg = t & 3, sg = (t >> 2) & 3, slice = t >> 4;

    float4 acc4[4][4];
#pragma unroll
    for (int k = 0; k < 4; k++)
#pragma unroll
        for (int j = 0; j < 4; j++) acc4[k][j] = make_float4(0.f, 0.f, 0.f, 0.f);

    const float* xb = x + (size_t)b * CCH * HW + n0;
    const float* Mb = M + (size_t)b * CCH * S2P + (size_t)c0 * S2P;

    // stage xs: 384 f4 (256 + 128)
    {
        int r = t >> 2, cq = t & 3;
        *(float4*)&xs[r * XSP + 4 * cq] = *(const float4*)&xb[(size_t)(c0 + r) * HW + 4 * cq];
        if (t < 128) {
            int idx2 = t + 256;
            int r2 = idx2 >> 2, cq2 = idx2 & 3;
            *(float4*)&xs[r2 * XSP + 4 * cq2] = *(const float4*)&xb[(size_t)(c0 + r2) * HW + 4 * cq2];
        }
    }
    // stage Ms: 1248 f4 (4*256 + 224)
    {
#pragma unroll
        for (int k = 0; k < 4; k++) {
            int idx = t + 256 * k;
            *(float4*)&Ms[4 * idx] = *(const float4*)&Mb[4 * idx];
        }
        if (t < 224) {
            int idx = t + 1024;
            *(float4*)&Ms[4 * idx] = *(const float4*)&Mb[4 * idx];
        }
    }
    __syncthreads();

    int rbase = 6 * slice;
#pragma unroll
    for (int m = 0; m < 6; m++) {
        int r = rbase + m;
        const float4 xv = *(const float4*)&xs[r * XSP + 4 * pxg];
#pragma unroll
        for (int k = 0; k < 3; k++) {
            int g = sg + 4 * k;
            const float4 mv = *(const float4*)&Ms[r * S2P + 4 * g];
            acc4[k][0].x += mv.x * xv.x; acc4[k][0].y += mv.x * xv.y;
            acc4[k][0].z += mv.x * xv.z; acc4[k][0].w += mv.x * xv.w;
            acc4[k][1].x += mv.y * xv.x; acc4[k][1].y += mv.y * xv.y;
            acc4[k][1].z += mv.y * xv.z; acc4[k][1].w += mv.y * xv.w;
            acc4[k][2].x += mv.z * xv.x; acc4[k][2].y += mv.z * xv.y;
            acc4[k][2].z += mv.z * xv.z; acc4[k][2].w += mv.z * xv.w;
            acc4[k][3].x += mv.w * xv.x; acc4[k][3].y += mv.w * xv.y;
            acc4[k][3].z += mv.w * xv.z; acc4[k][3].w += mv.w * xv.w;
        }
        if (sg == 0) {
            const float4 mv = *(const float4*)&Ms[r * S2P + 48];
            acc4[3][0].x += mv.x * xv.x; acc4[3][0].y += mv.x * xv.y;
            acc4[3][0].z += mv.x * xv.z; acc4[3][0].w += mv.x * xv.w;
            acc4[3][1].x += mv.y * xv.x; acc4[3][1].y += mv.y * xv.y;
            acc4[3][1].z += mv.y * xv.z; acc4[3][1].w += mv.y * xv.w;
            acc4[3][2].x += mv.z * xv.x; acc4[3][2].y += mv.z * xv.y;
            acc4[3][2].z += mv.z * xv.z; acc4[3][2].w += mv.z * xv.w;
            acc4[3][3].x += mv.w * xv.x; acc4[3][3].y += mv.w * xv.y;
            acc4[3][3].z += mv.w * xv.z; acc4[3][3].w += mv.w * xv.w;
        }
    }

    // in-wave reduce across 4 slice-groups of this wave (lane^16, lane^32)
#pragma unroll
    for (int k = 0; k < 4; k++)
#pragma unroll
        for (int j = 0; j < 4; j++) {
            acc4[k][j].x += __shfl_xor(acc4[k][j].x, 16);
            acc4[k][j].y += __shfl_xor(acc4[k][j].y, 16);
            acc4[k][j].z += __shfl_xor(acc4[k][j].z, 16);
            acc4[k][j].w += __shfl_xor(acc4[k][j].w, 16);
            acc4[k][j].x += __shfl_xor(acc4[k][j].x, 32);
            acc4[k][j].y += __shfl_xor(acc4[k][j].y, 32);
            acc4[k][j].z += __shfl_xor(acc4[k][j].z, 32);
            acc4[k][j].w += __shfl_xor(acc4[k][j].w, 32);
        }
    __syncthreads();   // all waves done reading xs/Ms before red overwrites

    // wave partials -> red[wave][16px][52]
    if ((t & 63) < 16) {
        int wv = t >> 6;
        float* rb = red + (size_t)wv * 16 * S2P;
#pragma unroll
        for (int k = 0; k < 4; k++) {
            int g = sg + 4 * k;
            if (g < 13) {
                *(float4*)&rb[(4 * pxg + 0) * S2P + 4 * g] =
                    make_float4(acc4[k][0].x, acc4[k][1].x, acc4[k][2].x, acc4[k][3].x);
                *(float4*)&rb[(4 * pxg + 1) * S2P + 4 * g] =
                    make_float4(acc4[k][0].y, acc4[k][1].y, acc4[k][2].y, acc4[k][3].y);
                *(float4*)&rb[(4 * pxg + 2) * S2P + 4 * g] =
                    make_float4(acc4[k][0].z, acc4[k][1].z, acc4[k][2].z, acc4[k][3].z);
                *(float4*)&rb[(4 * pxg + 3) * S2P + 4 * g] =
                    make_float4(acc4[k][0].w, acc4[k][1].w, acc4[k][2].w, acc4[k][3].w);
            }
        }
    }
    __syncthreads();

    // reduce 4 waves -> contiguous partial record (16*52 floats) in global
    float* pb = part + ((size_t)blk) * (16 * S2P);
    if (t < 208) {
        int px = t / 13, q = t - px * 13;
        float4 ssum = make_float4(0.f, 0.f, 0.f, 0.f);
#pragma unroll
        for (int wv = 0; wv < 4; wv++) {
            float4 vv = *(float4*)&red[(size_t)(wv * 16 + px) * S2P + 4 * q];
            ssum.x += vv.x; ssum.y += vv.y; ssum.z += vv.z; ssum.w += vv.w;
        }
        *(float4*)&pb[px * S2P + 4 * q] = ssum;
    }
}

// ---- Kernel 3b: sum 4 chunk-partials, softmax(49), dyn = Wwd*A ----
// grid = 4b*196 tiles, 256 thr, 16 px/block.
__global__ __launch_bounds__(256) void attn_b(const float* __restrict__ part,
                                              const float* __restrict__ Wwd,
                                              float* __restrict__ dyn) {
    __shared__ __align__(16) float sc[16 * S2P];
    __shared__ __align__(16) float wl[K2 * S2P];
    int blk  = blockIdx.x;
    int tile = blk % 196;
    int b    = blk / 196;
    int n0   = tile * 16;
    int t    = threadIdx.x;

    if (t < 208) {
        int px = t / 13, q = t - px * 13;
        float4 ssum = make_float4(0.f, 0.f, 0.f, 0.f);
#pragma unroll
        for (int ch = 0; ch < 4; ch++) {
            const float* pb = part + ((size_t)(ch * 784 + b * 196 + tile)) * (16 * S2P);
            float4 vv = *(const float4*)&pb[px * S2P + 4 * q];
            ssum.x += vv.x; ssum.y += vv.y; ssum.z += vv.z; ssum.w += vv.w;
        }
        *(float4*)&sc[px * S2P + 4 * q] = ssum;
    }
    __syncthreads();

    // softmax (t<128: 8 lanes/px) | Wwd staging (t>=128)
    if (t < 128) {
        int px = t >> 3, li = t & 7;
        float mx = -3.4e38f;
#pragma unroll
        for (int k = 0; k < 7; k++) { int s = li + 8 * k; if (s < S2) mx = fmaxf(mx, sc[px * S2P + s]); }
        mx = fmaxf(mx, __shfl_xor(mx, 1, 8));
        mx = fmaxf(mx, __shfl_xor(mx, 2, 8));
        mx = fmaxf(mx, __shfl_xor(mx, 4, 8));
        float e[7]; float sum = 0.f;
#pragma unroll
        for (int k = 0; k < 7; k++) {
            int s = li + 8 * k;
            if (s < S2) { e[k] = __expf(sc[px * S2P + s] - mx); sum += e[k]; }
        }
        sum += __shfl_xor(sum, 1, 8);
        sum += __shfl_xor(sum, 2, 8);
        sum += __shfl_xor(sum, 4, 8);
        float inv = 1.f / sum;
#pragma unroll
        for (int k = 0; k < 7; k++) {
            int s = li + 8 * k;
            if (s < S2) sc[px * S2P + s] = e[k] * inv;
        }
    } else {
        int u = t - 128;
#pragma unroll
        for (int k = 0; k < 10; k++) {
            int i = u + 128 * k;
            int j = i / S2P, ss = i - j * S2P;
            wl[i] = (ss < S2) ? Wwd[j * S2 + ss] : 0.f;
        }
        if (u < 20) {
            int i = u + 1280;
            int j = i / S2P, ss = i - j * S2P;
            wl[i] = (ss < S2) ? Wwd[j * S2 + ss] : 0.f;
        }
    }
    __syncthreads();

    // dyn[b,j,n0+px] = sum_s wl[j,s]*sc[px,s]   (400 outs: 256 + 144)
    float* dynb = dyn + (size_t)b * K2 * HW + n0;
#pragma unroll
    for (int pass = 0; pass < 2; pass++) {
        int o = t + 256 * pass;
        if (pass == 0 || t < 144) {
            int j = o >> 4, px = o & 15;
            float a = 0.f;
#pragma unroll
            for (int q = 0; q < 13; q++) {
                float4 wv = *(float4*)&wl[j * S2P + 4 * q];
                float4 pv = *(float4*)&sc[px * S2P + 4 * q];
                a += wv.x * pv.x + wv.y * pv.y + wv.z * pv.z + wv.w * pv.w;
            }
            dynb[(size_t)j * HW + px] = a;
        }
    }
}

// ---- Kernel 4: 5x5 dynamic stencil; 16 ch x 8-row stripe ----
__global__ __launch_bounds__(256) void out_k(const float* __restrict__ x,
                                             const float* __restrict__ dyn,
                                             float* __restrict__ out) {
    __shared__ __align__(16) float xt[16][12][60];
    int blk    = blockIdx.x;
    int stripe = blk % 7;
    int cg     = (blk / 7) % 24;
    int b      = blk / (7 * 24);
    int h0 = stripe * 8;
    int c0 = cg * 16;
    int t  = threadIdx.x;
    const float* xb = x + ((size_t)(b * CCH + c0)) * HW;

    if (t < 192) {
        int cc = t / 12, r = t % 12;
        xt[cc][r][0] = 0.f; xt[cc][r][1] = 0.f;
        xt[cc][r][58] = 0.f; xt[cc][r][59] = 0.f;
    }
#pragma unroll
    for (int k = 0; k < 11; k++) {
        int idx = t + 256 * k;
        if (k < 10 || t < 128) {
            int cc  = idx / 168;
            int rem = idx - cc * 168;
            int r   = rem / 14;
            int q   = rem - r * 14;
            int h   = h0 - 2 + r;
            float4 v = make_float4(0.f, 0.f, 0.f, 0.f);
            if ((unsigned)h < (unsigned)HH)
                v = *(const float4*)&xb[(size_t)cc * HW + h * WWD + 4 * q];
            xt[cc][r][2 + 4 * q + 0] = v.x;
            xt[cc][r][2 + 4 * q + 1] = v.y;
            xt[cc][r][2 + 4 * q + 2] = v.z;
            xt[cc][r][2 + 4 * q + 3] = v.w;
        }
    }

    bool act = t < 224;
    int r  = t / 28;
    int w0 = 2 * (t % 28);
    int n  = (h0 + r) * WWD + w0;
    float2 dv[K2];
    if (act) {
        const float* db = dyn + (size_t)b * K2 * HW + n;
#pragma unroll
        for (int j = 0; j < K2; j++) dv[j] = *(const float2*)&db[(size_t)j * HW];
    }
    __syncthreads();
    if (!act) return;

    float* ob = out + ((size_t)(b * CCH + c0)) * HW + n;
#pragma unroll
    for (int cc = 0; cc < 16; cc++) {
        float ax = 0.f, ay = 0.f;
#pragma unroll
        for (int rr = 0; rr < 5; rr++) {
            int lr = r + rr;
            float2 p0 = *(float2*)&xt[cc][lr][w0];
            float2 p1 = *(float2*)&xt[cc][lr][w0 + 2];
            float2 p2 = *(float2*)&xt[cc][lr][w0 + 4];
            int o5 = rr * 5;
            ax += p0.x * dv[o5].x     + p0.y * dv[o5 + 1].x + p1.x * dv[o5 + 2].x
                + p1.y * dv[o5 + 3].x + p2.x * dv[o5 + 4].x;
            ay += p0.y * dv[o5].y     + p1.x * dv[o5 + 1].y + p1.y * dv[o5 + 2].y
                + p2.x * dv[o5 + 3].y + p2.y * dv[o5 + 4].y;
        }
        *(float2*)&ob[(size_t)cc * HW] = make_float2(ax, ay);
    }
}

extern "C" void kernel_launch(void* const* d_in, const int* in_sizes, int n_in,
                              void* d_out, int out_size, void* d_ws, size_t ws_size,
                              hipStream_t stream) {
    const float* x   = (const float*)d_in[0];
    const float* ctx = (const float*)d_in[1];
    const float* Wq  = (const float*)d_in[2];
    const float* Wk  = (const float*)d_in[3];
    const float* Wwd = (const float*)d_in[4];
    float* out = (float*)d_out;
    float* ws  = (float*)d_ws;

    float* GT    = ws;                           // 384*384          = 147456
    float* M     = ws + 147456;                  // B*384*52         =  79872
    float* dyn   = ws + 227328;                  // B*25*3136        = 313600
    float* ctx_p = ws + 540928;                  // B*384*49         =  75264
    float* part  = ws + 616192;                  // 16*196*16*52     = 2609152

    gt_k<<<12 * 12, 256, 0, stream>>>(Wk, Wq, GT);
    pool2_k<<<BB * CCH, 256, 0, stream>>>(ctx, ctx_p);
    m2_k<<<BB * S2, 384, 0, stream>>>(ctx_p, GT, M);
    attn_a<<<4 * BB * 196, 256, 0, stream>>>(x, M, part);
    attn_b<<<BB * 196, 256, 0, stream>>>(part, Wwd, dyn);
    out_k<<<BB * 24 * 7, 256, 0, stream>>>(x, dyn, out);
}

// Round 9
// 166.609 us; speedup vs baseline: 1.1637x; 1.1060x over previous
//
#include <hip/hip_runtime.h>

#define BB 4
#define CCH 384
#define HH 56
#define WWD 56
#define HW 3136
#define S2 49
#define S2P 52
#define D2 192
#define K2 25

// ---- Kernel 1: GT[i][j] = sum_d Wk[d][i] * Wq[d][j]  (384x384, K=192) ----
__global__ __launch_bounds__(256) void gt_k(const float* __restrict__ Wk,
                                            const float* __restrict__ Wq,
                                            float* __restrict__ GT) {
    __shared__ __align__(16) float As[D2 * 32];
    __shared__ __align__(16) float Bs[D2 * 32];
    int bi = blockIdx.x % 12, bj = blockIdx.x / 12;
    int t = threadIdx.x;
#pragma unroll
    for (int k = 0; k < 6; k++) {
        int idx = t + 256 * k;
        int d = idx >> 3, q = idx & 7;
        *(float4*)&As[d * 32 + 4 * q] = *(const float4*)&Wk[(size_t)d * CCH + bi * 32 + 4 * q];
        *(float4*)&Bs[d * 32 + 4 * q] = *(const float4*)&Wq[(size_t)d * CCH + bj * 32 + 4 * q];
    }
    __syncthreads();
    int ti = t >> 4, tj = t & 15;
    float a00 = 0.f, a01 = 0.f, a10 = 0.f, a11 = 0.f;
#pragma unroll 8
    for (int d = 0; d < D2; d++) {
        float2 av = *(float2*)&As[d * 32 + 2 * ti];
        float2 bv = *(float2*)&Bs[d * 32 + 2 * tj];
        a00 += av.x * bv.x; a01 += av.x * bv.y;
        a10 += av.y * bv.x; a11 += av.y * bv.y;
    }
    int gi = bi * 32 + 2 * ti, gj = bj * 32 + 2 * tj;
    *(float2*)&GT[(size_t)gi * CCH + gj]       = make_float2(a00, a01);
    *(float2*)&GT[(size_t)(gi + 1) * CCH + gj] = make_float2(a10, a11);
}

// ---- Kernel 2a: coalesced adaptive pool: block per (b,c), f4 sweep + LDS bins
__global__ __launch_bounds__(256) void pool2_k(const float* __restrict__ ctx,
                                               float* __restrict__ ctx_p) {
    __shared__ float bin[S2];
    int bc = blockIdx.x;
    int t  = threadIdx.x;
    if (t < S2) bin[t] = 0.f;
    __syncthreads();
    const float* img = ctx + (size_t)bc * HW;
#pragma unroll
    for (int k = 0; k < 4; k++) {
        int i = t + 256 * k;
        if (k < 3 || t < 16) {
            float4 a = *(const float4*)&img[4 * i];
            float s4 = a.x + a.y + a.z + a.w;
            int h  = i / 14;
            int rc = i - 14 * h;
            int sy = h >> 3, sx = rc >> 1;
            atomicAdd(&bin[sy * 7 + sx], s4);
        }
    }
    __syncthreads();
    if (t < S2) ctx_p[(size_t)bc * S2 + t] = bin[t] * (1.f / 64.f);
}

// ---- Kernel 2b: M[b,c,s] = sum_i ctx_p[b,i,s] * GT[i][c]  (per (b,s) block)
__global__ __launch_bounds__(384) void m2_k(const float* __restrict__ ctx_p,
                                            const float* __restrict__ GT,
                                            float* __restrict__ M) {
    __shared__ float v[CCH];
    int b = blockIdx.x / S2, s = blockIdx.x % S2;
    int t = threadIdx.x;
    v[t] = ctx_p[((size_t)(b * CCH) + t) * S2 + s];
    __syncthreads();
    float acc = 0.f;
#pragma unroll 8
    for (int i = 0; i < CCH; i++)
        acc += v[i] * GT[(size_t)i * CCH + t];
    M[((size_t)(b * CCH + t)) * S2P + s] = acc;
    if (s < 3) M[((size_t)(b * CCH + t)) * S2P + 49 + s] = 0.f;
}

// ---- Kernel 3a: partial scores, 64-px tile x 96-ch chunk ----
// grid = 4ch * 4b * 49 tiles = 784; 256 thr; wave w owns px window 16w..16w+15.
// Roles in wave: pxg=t&3, sg=(t>>2)&3, slice=(t>>4)&3 (4 c-slices x 24 rows).
__global__ __launch_bounds__(256) void attn_a(const float* __restrict__ x,
                                              const float* __restrict__ M,
                                              float* __restrict__ part) {
    __shared__ __align__(16) float smem[96 * 64 + 96 * S2P]; // xs[96][64] | Ms[96][52]
    float* xs  = smem;               // [96][64]
    float* Ms  = smem + 6144;        // [96][52]
    float* red = smem;               // [4 waves][16 px][52] = 3328 floats (aliases xs)

    int blk  = blockIdx.x;
    int t64  = blk % 49;
    int b    = (blk / 49) & 3;
    int ch   = blk / 196;
    int n0   = t64 * 64;
    int c0   = ch * 96;
    int t    = threadIdx.x;
    int w    = t >> 6;
    int lane = t & 63;
    int pxg = t & 3, sg = (t >> 2) & 3, slice = (t >> 4) & 3;

    float4 acc4[4][4];
#pragma unroll
    for (int k = 0; k < 4; k++)
#pragma unroll
        for (int j = 0; j < 4; j++) acc4[k][j] = make_float4(0.f, 0.f, 0.f, 0.f);

    const float* xb = x + (size_t)b * CCH * HW + n0;
    const float* Mb = M + (size_t)b * CCH * S2P + (size_t)c0 * S2P;

    // stage xs: 96 rows x 16 f4 = 1536 f4 (6 per thread, exact)
#pragma unroll
    for (int k = 0; k < 6; k++) {
        int idx = t + 256 * k;
        int r = idx >> 4, q = idx & 15;
        *(float4*)&xs[r * 64 + 4 * q] = *(const float4*)&xb[(size_t)(c0 + r) * HW + 4 * q];
    }
    // stage Ms: 1248 f4 (4*256 + 224), contiguous
#pragma unroll
    for (int k = 0; k < 4; k++) {
        int idx = t + 256 * k;
        *(float4*)&Ms[4 * idx] = *(const float4*)&Mb[4 * idx];
    }
    if (t < 224) {
        int idx = t + 1024;
        *(float4*)&Ms[4 * idx] = *(const float4*)&Mb[4 * idx];
    }
    __syncthreads();

    int rbase = 24 * slice;
    int xcol  = 16 * w + 4 * pxg;
#pragma unroll 4
    for (int m = 0; m < 24; m++) {
        int r = rbase + m;
        const float4 xv = *(const float4*)&xs[r * 64 + xcol];
#pragma unroll
        for (int k = 0; k < 3; k++) {
            int g = sg + 4 * k;
            const float4 mv = *(const float4*)&Ms[r * S2P + 4 * g];
            acc4[k][0].x += mv.x * xv.x; acc4[k][0].y += mv.x * xv.y;
            acc4[k][0].z += mv.x * xv.z; acc4[k][0].w += mv.x * xv.w;
            acc4[k][1].x += mv.y * xv.x; acc4[k][1].y += mv.y * xv.y;
            acc4[k][1].z += mv.y * xv.z; acc4[k][1].w += mv.y * xv.w;
            acc4[k][2].x += mv.z * xv.x; acc4[k][2].y += mv.z * xv.y;
            acc4[k][2].z += mv.z * xv.z; acc4[k][2].w += mv.z * xv.w;
            acc4[k][3].x += mv.w * xv.x; acc4[k][3].y += mv.w * xv.y;
            acc4[k][3].z += mv.w * xv.z; acc4[k][3].w += mv.w * xv.w;
        }
        if (sg == 0) {
            const float4 mv = *(const float4*)&Ms[r * S2P + 48];
            acc4[3][0].x += mv.x * xv.x; acc4[3][0].y += mv.x * xv.y;
            acc4[3][0].z += mv.x * xv.z; acc4[3][0].w += mv.x * xv.w;
            acc4[3][1].x += mv.y * xv.x; acc4[3][1].y += mv.y * xv.y;
            acc4[3][1].z += mv.y * xv.z; acc4[3][1].w += mv.y * xv.w;
            acc4[3][2].x += mv.z * xv.x; acc4[3][2].y += mv.z * xv.y;
            acc4[3][2].z += mv.z * xv.z; acc4[3][2].w += mv.z * xv.w;
            acc4[3][3].x += mv.w * xv.x; acc4[3][3].y += mv.w * xv.y;
            acc4[3][3].z += mv.w * xv.z; acc4[3][3].w += mv.w * xv.w;
        }
    }

    // in-wave reduce across the 4 c-slices (lane^16, lane^32)
#pragma unroll
    for (int k = 0; k < 4; k++)
#pragma unroll
        for (int j = 0; j < 4; j++) {
            acc4[k][j].x += __shfl_xor(acc4[k][j].x, 16);
            acc4[k][j].y += __shfl_xor(acc4[k][j].y, 16);
            acc4[k][j].z += __shfl_xor(acc4[k][j].z, 16);
            acc4[k][j].w += __shfl_xor(acc4[k][j].w, 16);
            acc4[k][j].x += __shfl_xor(acc4[k][j].x, 32);
            acc4[k][j].y += __shfl_xor(acc4[k][j].y, 32);
            acc4[k][j].z += __shfl_xor(acc4[k][j].z, 32);
            acc4[k][j].w += __shfl_xor(acc4[k][j].w, 32);
        }
    __syncthreads();   // all waves done reading xs before red overwrites

    // lanes<16 of each wave write its 16px x 52 result -> red[w][px][s]
    if (lane < 16) {
        float* rb = red + (size_t)w * 16 * S2P;
#pragma unroll
        for (int k = 0; k < 4; k++) {
            int g = sg + 4 * k;
            if (g < 13) {
                *(float4*)&rb[(4 * pxg + 0) * S2P + 4 * g] =
                    make_float4(acc4[k][0].x, acc4[k][1].x, acc4[k][2].x, acc4[k][3].x);
                *(float4*)&rb[(4 * pxg + 1) * S2P + 4 * g] =
                    make_float4(acc4[k][0].y, acc4[k][1].y, acc4[k][2].y, acc4[k][3].y);
                *(float4*)&rb[(4 * pxg + 2) * S2P + 4 * g] =
                    make_float4(acc4[k][0].z, acc4[k][1].z, acc4[k][2].z, acc4[k][3].z);
                *(float4*)&rb[(4 * pxg + 3) * S2P + 4 * g] =
                    make_float4(acc4[k][0].w, acc4[k][1].w, acc4[k][2].w, acc4[k][3].w);
            }
        }
    }
    __syncthreads();

    // coalesced copy red -> part record (64*52 = 832 f4: 3*256 + 64)
    float* pb = part + (size_t)blk * (64 * S2P);
#pragma unroll
    for (int pass = 0; pass < 4; pass++) {
        int idx = t + 256 * pass;
        if (pass < 3 || t < 64)
            *(float4*)&pb[4 * idx] = *(float4*)&red[4 * idx];
    }
}

// ---- Kernel 3b: sum 4 chunk-partials, softmax(49), dyn = Wwd*A ----
// grid = 4b*196 tiles, 256 thr, 16 px/block.
__global__ __launch_bounds__(256) void attn_b(const float* __restrict__ part,
                                              const float* __restrict__ Wwd,
                                              float* __restrict__ dyn) {
    __shared__ __align__(16) float sc[16 * S2P];
    __shared__ __align__(16) float wl[K2 * S2P];
    int blk  = blockIdx.x;
    int tile = blk % 196;
    int b    = blk / 196;
    int n0   = tile * 16;
    int t64  = tile >> 2;          // 64-px tile index
    int sub  = tile & 3;           // 16-px window within it
    int t    = threadIdx.x;

    if (t < 208) {
        int px = t / 13, q = t - px * 13;
        float4 ssum = make_float4(0.f, 0.f, 0.f, 0.f);
#pragma unroll
        for (int ch = 0; ch < 4; ch++) {
            const float* pb = part + ((size_t)((ch * 4 + b) * 49 + t64)) * (64 * S2P)
                                   + (size_t)sub * 16 * S2P;
            float4 vv = *(const float4*)&pb[px * S2P + 4 * q];
            ssum.x += vv.x; ssum.y += vv.y; ssum.z += vv.z; ssum.w += vv.w;
        }
        *(float4*)&sc[px * S2P + 4 * q] = ssum;
    }
    __syncthreads();

    // softmax (t<128: 8 lanes/px) | Wwd staging (t>=128)
    if (t < 128) {
        int px = t >> 3, li = t & 7;
        float mx = -3.4e38f;
#pragma unroll
        for (int k = 0; k < 7; k++) { int s = li + 8 * k; if (s < S2) mx = fmaxf(mx, sc[px * S2P + s]); }
        mx = fmaxf(mx, __shfl_xor(mx, 1, 8));
        mx = fmaxf(mx, __shfl_xor(mx, 2, 8));
        mx = fmaxf(mx, __shfl_xor(mx, 4, 8));
        float e[7]; float sum = 0.f;
#pragma unroll
        for (int k = 0; k < 7; k++) {
            int s = li + 8 * k;
            if (s < S2) { e[k] = __expf(sc[px * S2P + s] - mx); sum += e[k]; }
        }
        sum += __shfl_xor(sum, 1, 8);
        sum += __shfl_xor(sum, 2, 8);
        sum += __shfl_xor(sum, 4, 8);
        float inv = 1.f / sum;
#pragma unroll
        for (int k = 0; k < 7; k++) {
            int s = li + 8 * k;
            if (s < S2) sc[px * S2P + s] = e[k] * inv;
        }
    } else {
        int u = t - 128;
#pragma unroll
        for (int k = 0; k < 10; k++) {
            int i = u + 128 * k;
            int j = i / S2P, ss = i - j * S2P;
            wl[i] = (ss < S2) ? Wwd[j * S2 + ss] : 0.f;
        }
        if (u < 20) {
            int i = u + 1280;
            int j = i / S2P, ss = i - j * S2P;
            wl[i] = (ss < S2) ? Wwd[j * S2 + ss] : 0.f;
        }
    }
    __syncthreads();

    // dyn[b,j,n0+px] = sum_s wl[j,s]*sc[px,s]   (400 outs: 256 + 144)
    float* dynb = dyn + (size_t)b * K2 * HW + n0;
#pragma unroll
    for (int pass = 0; pass < 2; pass++) {
        int o = t + 256 * pass;
        if (pass == 0 || t < 144) {
            int j = o >> 4, px = o & 15;
            float a = 0.f;
#pragma unroll
            for (int q = 0; q < 13; q++) {
                float4 wv = *(float4*)&wl[j * S2P + 4 * q];
                float4 pv = *(float4*)&sc[px * S2P + 4 * q];
                a += wv.x * pv.x + wv.y * pv.y + wv.z * pv.z + wv.w * pv.w;
            }
            dynb[(size_t)j * HW + px] = a;
        }
    }
}

// ---- Kernel 4: 5x5 dynamic stencil; 16 ch x 8-row stripe ----
__global__ __launch_bounds__(256) void out_k(const float* __restrict__ x,
                                             const float* __restrict__ dyn,
                                             float* __restrict__ out) {
    __shared__ __align__(16) float xt[16][12][60];
    int blk    = blockIdx.x;
    int stripe = blk % 7;
    int cg     = (blk / 7) % 24;
    int b      = blk / (7 * 24);
    int h0 = stripe * 8;
    int c0 = cg * 16;
    int t  = threadIdx.x;
    const float* xb = x + ((size_t)(b * CCH + c0)) * HW;

    if (t < 192) {
        int cc = t / 12, r = t % 12;
        xt[cc][r][0] = 0.f; xt[cc][r][1] = 0.f;
        xt[cc][r][58] = 0.f; xt[cc][r][59] = 0.f;
    }
#pragma unroll
    for (int k = 0; k < 11; k++) {
        int idx = t + 256 * k;
        if (k < 10 || t < 128) {
            int cc  = idx / 168;
            int rem = idx - cc * 168;
            int r   = rem / 14;
            int q   = rem - r * 14;
            int h   = h0 - 2 + r;
            float4 v = make_float4(0.f, 0.f, 0.f, 0.f);
            if ((unsigned)h < (unsigned)HH)
                v = *(const float4*)&xb[(size_t)cc * HW + h * WWD + 4 * q];
            xt[cc][r][2 + 4 * q + 0] = v.x;
            xt[cc][r][2 + 4 * q + 1] = v.y;
            xt[cc][r][2 + 4 * q + 2] = v.z;
            xt[cc][r][2 + 4 * q + 3] = v.w;
        }
    }

    bool act = t < 224;
    int r  = t / 28;
    int w0 = 2 * (t % 28);
    int n  = (h0 + r) * WWD + w0;
    float2 dv[K2];
    if (act) {
        const float* db = dyn + (size_t)b * K2 * HW + n;
#pragma unroll
        for (int j = 0; j < K2; j++) dv[j] = *(const float2*)&db[(size_t)j * HW];
    }
    __syncthreads();
    if (!act) return;

    float* ob = out + ((size_t)(b * CCH + c0)) * HW + n;
#pragma unroll
    for (int cc = 0; cc < 16; cc++) {
        float ax = 0.f, ay = 0.f;
#pragma unroll
        for (int rr = 0; rr < 5; rr++) {
            int lr = r + rr;
            float2 p0 = *(float2*)&xt[cc][lr][w0];
            float2 p1 = *(float2*)&xt[cc][lr][w0 + 2];
            float2 p2 = *(float2*)&xt[cc][lr][w0 + 4];
            int o5 = rr * 5;
            ax += p0.x * dv[o5].x     + p0.y * dv[o5 + 1].x + p1.x * dv[o5 + 2].x
                + p1.y * dv[o5 + 3].x + p2.x * dv[o5 + 4].x;
            ay += p0.y * dv[o5].y     + p1.x * dv[o5 + 1].y + p1.y * dv[o5 + 2].y
                + p2.x * dv[o5 + 3].y + p2.y * dv[o5 + 4].y;
        }
        *(float2*)&ob[(size_t)cc * HW] = make_float2(ax, ay);
    }
}

extern "C" void kernel_launch(void* const* d_in, const int* in_sizes, int n_in,
                              void* d_out, int out_size, void* d_ws, size_t ws_size,
                              hipStream_t stream) {
    const float* x   = (const float*)d_in[0];
    const float* ctx = (const float*)d_in[1];
    const float* Wq  = (const float*)d_in[2];
    const float* Wk  = (const float*)d_in[3];
    const float* Wwd = (const float*)d_in[4];
    float* out = (float*)d_out;
    float* ws  = (float*)d_ws;

    float* GT    = ws;                           // 384*384          = 147456
    float* M     = ws + 147456;                  // B*384*52         =  79872
    float* dyn   = ws + 227328;                  // B*25*3136        = 313600
    float* ctx_p = ws + 540928;                  // B*384*49         =  75264
    float* part  = ws + 616192;                  // 784*64*52        = 2609152

    gt_k<<<12 * 12, 256, 0, stream>>>(Wk, Wq, GT);
    pool2_k<<<BB * CCH, 256, 0, stream>>>(ctx, ctx_p);
    m2_k<<<BB * S2, 384, 0, stream>>>(ctx_p, GT, M);
    attn_a<<<4 * BB * 49, 256, 0, stream>>>(x, M, part);
    attn_b<<<BB * 196, 256, 0, stream>>>(part, Wwd, dyn);
    out_k<<<BB * 24 * 7, 256, 0, stream>>>(x, dyn, out);
}